// Round 1
// baseline (184.721 us; speedup 1.0000x reference)
//
#include <hip/hip_runtime.h>
#include <math.h>

#define NBC   16          // b*2
#define NF    160
#define NT    1000
#define NTQ   1003        // t rows incl. 3 pad rows at front

// ---------------------------------------------------------------------------
// k1: P[bc][fo][t] = sum_fi ql_w[fo][fi] * (sgn_c * far[bc][fi][t])
// block: 512 thr = 8 waves (each wave one 20-row fo group) x 64 t
// X tile (160 x 64) staged in LDS once, shared by all 8 fo-groups.
// ---------------------------------------------------------------------------
__global__ __launch_bounds__(512) void k1_qproj(const float* __restrict__ far,
                                                const float* __restrict__ qlw,
                                                float* __restrict__ P) {
    __shared__ float Xs[NF * 64];
    const int bc = blockIdx.x;      // 0..15
    const int t0 = blockIdx.y * 64; // 0..960
    const int tid = threadIdx.x;
    const int c = bc & 1;
    const float sgn = c ? -1.f : 1.f;
    const float* Xb = far + (size_t)bc * NF * NT;

    #pragma unroll
    for (int i = 0; i < 20; ++i) {
        int o = tid + i * 512;
        int fi = o >> 6, tl = o & 63;
        int t = t0 + tl;
        float v = (t < NT) ? Xb[fi * NT + t] : 0.f;
        Xs[fi * 64 + tl] = v * sgn;
    }
    __syncthreads();

    const int g = __builtin_amdgcn_readfirstlane(tid >> 6); // 0..7, wave-uniform
    const int tl = tid & 63;
    const int fo0 = g * 20;

    float acc[20];
    #pragma unroll
    for (int u = 0; u < 20; ++u) acc[u] = 0.f;

    #pragma unroll 4
    for (int fi = 0; fi < NF; ++fi) {
        float x = Xs[fi * 64 + tl];
        #pragma unroll
        for (int u = 0; u < 20; ++u)
            acc[u] = fmaf(qlw[(fo0 + u) * NF + fi], x, acc[u]);
    }

    int t = t0 + tl;
    if (t < NT) {
        float* Pb = P + (size_t)bc * NF * NT;
        #pragma unroll
        for (int u = 0; u < 20; ++u) Pb[(fo0 + u) * NT + t] = acc[u];
    }
}

// ---------------------------------------------------------------------------
// k2: Qn[bc][tt][f] = LN(P[bc][:,tt-3] + ql_b) * qn_g + qn_b, * sigmoid(q_vec)
// tt in [0,1003); tt<3 -> padded zero input row.
// ---------------------------------------------------------------------------
__global__ __launch_bounds__(256) void k2_ln(const float* __restrict__ P,
                                             const float* __restrict__ qlb,
                                             const float* __restrict__ qng,
                                             const float* __restrict__ qnb,
                                             const float* __restrict__ qvec,
                                             float* __restrict__ Qn) {
    const int bc = blockIdx.x;
    const int tt = blockIdx.y * 256 + threadIdx.x;
    if (tt >= NTQ) return;
    const int t = tt - 3;
    const float* Pb = P + (size_t)bc * NF * NT;

    float sum = 0.f, sumsq = 0.f;
    for (int fo = 0; fo < NF; ++fo) {
        float v = (t >= 0 ? Pb[fo * NT + t] : 0.f) + qlb[fo];
        sum += v;
        sumsq = fmaf(v, v, sumsq);
    }
    float mean = sum * (1.f / NF);
    float var = sumsq * (1.f / NF) - mean * mean;
    float inv = 1.f / sqrtf(var + 1e-5f);

    float* Qb = Qn + (size_t)bc * NTQ * NF + (size_t)tt * NF;
    for (int fo = 0; fo < NF; ++fo) {
        float v = (t >= 0 ? Pb[fo * NT + t] : 0.f) + qlb[fo];
        float q = (v - mean) * inv * qng[fo] + qnb[fo];
        float sq = 1.f / (1.f + expf(-qvec[fo]));
        Qb[fo] = q * sq;
    }
}

// ---------------------------------------------------------------------------
// k3: per (b,c,t): key pipeline over f, scores (4x4), softmax -> W[site][16]
// one wave per site; lanes split the 160 f values.
// ---------------------------------------------------------------------------
__global__ __launch_bounds__(256) void k3_attn(const float* __restrict__ mix,
                                               const float* __restrict__ Qn,
                                               const float* __restrict__ kcw,
                                               const float* __restrict__ kcb,
                                               const float* __restrict__ klw,
                                               const float* __restrict__ klb,
                                               const float* __restrict__ kng,
                                               const float* __restrict__ knb,
                                               const float* __restrict__ kvec,
                                               float* __restrict__ W) {
    const int wv = __builtin_amdgcn_readfirstlane((int)threadIdx.x >> 6);
    const int lane = threadIdx.x & 63;
    const int site = blockIdx.x * 4 + wv;   // bc*1000 + t
    if (site >= NBC * NT) return;
    const int bc = site / NT;
    const int t = site - bc * NT;
    const int b = bc >> 1, c = bc & 1;

    float kw0[4], kw1[4], kb[4], klwm[16], klbv[4], kngv[4], knbv[4], sigk[4];
    #pragma unroll
    for (int j = 0; j < 4; ++j) {
        kw0[j] = kcw[(4 * c + j) * 2 + 0];
        kw1[j] = kcw[(4 * c + j) * 2 + 1];
        kb[j]  = kcb[4 * c + j];
        klbv[j] = klb[j];
        kngv[j] = kng[j];
        knbv[j] = knb[j];
        sigk[j] = 0.5f / (1.f + expf(-kvec[j]));   // sigmoid(k_vec)/sqrt(k)
    }
    #pragma unroll
    for (int x = 0; x < 16; ++x) klwm[x] = klw[x];

    float s[16];
    #pragma unroll
    for (int x = 0; x < 16; ++x) s[x] = 0.f;

    const float* mixb = mix + (size_t)(b * 2) * NF * NT;
    const float* Qb = Qn + (size_t)bc * NTQ * NF;

    #pragma unroll
    for (int rep = 0; rep < 3; ++rep) {
        int f = lane + rep * 64;
        if (f < NF) {
            float m0 = mixb[f * NT + t];
            float m1 = mixb[NF * NT + f * NT + t];
            float kraw[4], klin[4];
            #pragma unroll
            for (int j = 0; j < 4; ++j)
                kraw[j] = fmaf(kw0[j], m0, fmaf(kw1[j], m1, kb[j]));
            #pragma unroll
            for (int jo = 0; jo < 4; ++jo) {
                float a = klbv[jo];
                #pragma unroll
                for (int ji = 0; ji < 4; ++ji) a = fmaf(klwm[jo * 4 + ji], kraw[ji], a);
                klin[jo] = a;
            }
            float mn = 0.25f * (klin[0] + klin[1] + klin[2] + klin[3]);
            float d0 = klin[0] - mn, d1 = klin[1] - mn, d2 = klin[2] - mn, d3 = klin[3] - mn;
            float var = 0.25f * (d0 * d0 + d1 * d1 + d2 * d2 + d3 * d3);
            float inv = 1.f / sqrtf(var + 1e-5f);
            float kn[4];
            kn[0] = (d0 * inv * kngv[0] + knbv[0]) * sigk[0];
            kn[1] = (d1 * inv * kngv[1] + knbv[1]) * sigk[1];
            kn[2] = (d2 * inv * kngv[2] + knbv[2]) * sigk[2];
            kn[3] = (d3 * inv * kngv[3] + knbv[3]) * sigk[3];

            float q0 = Qb[(t + 0) * NF + f];
            float q1 = Qb[(t + 1) * NF + f];
            float q2 = Qb[(t + 2) * NF + f];
            float q3 = Qb[(t + 3) * NF + f];
            #pragma unroll
            for (int j = 0; j < 4; ++j) {
                s[0 * 4 + j] = fmaf(q0, kn[j], s[0 * 4 + j]);
                s[1 * 4 + j] = fmaf(q1, kn[j], s[1 * 4 + j]);
                s[2 * 4 + j] = fmaf(q2, kn[j], s[2 * 4 + j]);
                s[3 * 4 + j] = fmaf(q3, kn[j], s[3 * 4 + j]);
            }
        }
    }

    #pragma unroll
    for (int off = 1; off < 64; off <<= 1) {
        #pragma unroll
        for (int x = 0; x < 16; ++x) s[x] += __shfl_xor(s[x], off, 64);
    }

    float wv16[16];
    #pragma unroll
    for (int i = 0; i < 4; ++i) {
        float a = s[i * 4 + 0], b2 = s[i * 4 + 1], c2 = s[i * 4 + 2], d2 = s[i * 4 + 3];
        float mx = fmaxf(fmaxf(a, b2), fmaxf(c2, d2));
        float e0 = expf(a - mx), e1 = expf(b2 - mx), e2 = expf(c2 - mx), e3 = expf(d2 - mx);
        float inv = 1.f / (e0 + e1 + e2 + e3);
        wv16[i * 4 + 0] = e0 * inv;
        wv16[i * 4 + 1] = e1 * inv;
        wv16[i * 4 + 2] = e2 * inv;
        wv16[i * 4 + 3] = e3 * inv;
    }
    if (lane < 16) {
        float v = 0.f;
        #pragma unroll
        for (int x = 0; x < 16; ++x) v = (lane == x) ? wv16[x] : v;
        W[(size_t)site * 16 + lane] = v;
    }
}

// ---------------------------------------------------------------------------
// complex 4x4 solve, partial pivoting (cabs1), fully unrolled
// ---------------------------------------------------------------------------
__device__ __forceinline__ void csolve4(float Ar[16], float Ai[16],
                                        float br[4], float bi[4],
                                        float wr[4], float wi[4]) {
    #pragma unroll
    for (int col = 0; col < 4; ++col) {
        #pragma unroll
        for (int r = col + 1; r < 4; ++r) {
            float cp = fabsf(Ar[col * 4 + col]) + fabsf(Ai[col * 4 + col]);
            float cr = fabsf(Ar[r * 4 + col]) + fabsf(Ai[r * 4 + col]);
            bool sw = cr > cp;
            #pragma unroll
            for (int m = col; m < 4; ++m) {
                float a0 = Ar[col * 4 + m], a1 = Ar[r * 4 + m];
                Ar[col * 4 + m] = sw ? a1 : a0;
                Ar[r * 4 + m]   = sw ? a0 : a1;
                float c0 = Ai[col * 4 + m], c1 = Ai[r * 4 + m];
                Ai[col * 4 + m] = sw ? c1 : c0;
                Ai[r * 4 + m]   = sw ? c0 : c1;
            }
            float b0 = br[col], b1 = br[r];
            br[col] = sw ? b1 : b0; br[r] = sw ? b0 : b1;
            float d0 = bi[col], d1 = bi[r];
            bi[col] = sw ? d1 : d0; bi[r] = sw ? d0 : d1;
        }
        float pr = Ar[col * 4 + col], pi = Ai[col * 4 + col];
        float den = 1.f / (pr * pr + pi * pi);
        #pragma unroll
        for (int r = col + 1; r < 4; ++r) {
            float nr = Ar[r * 4 + col], ni = Ai[r * 4 + col];
            float fr = (nr * pr + ni * pi) * den;
            float fi = (ni * pr - nr * pi) * den;
            #pragma unroll
            for (int m = col + 1; m < 4; ++m) {
                float tr = Ar[col * 4 + m], ti = Ai[col * 4 + m];
                Ar[r * 4 + m] -= fr * tr - fi * ti;
                Ai[r * 4 + m] -= fr * ti + fi * tr;
            }
            float tr = br[col], ti = bi[col];
            br[r] -= fr * tr - fi * ti;
            bi[r] -= fr * ti + fi * tr;
        }
    }
    #pragma unroll
    for (int col = 3; col >= 0; --col) {
        float sr = br[col], si = bi[col];
        #pragma unroll
        for (int m = col + 1; m < 4; ++m) {
            float tr = Ar[col * 4 + m], ti = Ai[col * 4 + m];
            sr -= tr * wr[m] - ti * wi[m];
            si -= tr * wi[m] + ti * wr[m];
        }
        float pr = Ar[col * 4 + col], pi = Ai[col * 4 + col];
        float den = 1.f / (pr * pr + pi * pi);
        wr[col] = (sr * pr + si * pi) * den;
        wi[col] = (si * pr - sr * pi) * den;
    }
}

// ---------------------------------------------------------------------------
// k4: per (b,f,t): build rank-1 value/out, assemble A,rhs, solve, Wiener sum
// ---------------------------------------------------------------------------
__global__ __launch_bounds__(256) void k4_final(const float* __restrict__ far,
                                                const float* __restrict__ mix,
                                                const float* __restrict__ Wt,
                                                const float* __restrict__ vvec,
                                                float* __restrict__ out) {
    const int t = blockIdx.x * 256 + threadIdx.x;
    const int f = blockIdx.y;
    const int b = blockIdx.z;
    if (t >= NT) return;

    const float* fr  = far + (size_t)(b * 2 + 0) * NF * NT + (size_t)f * NT;
    const float* fim = far + (size_t)(b * 2 + 1) * NF * NT + (size_t)f * NT;
    float ur[4], ui[4];
    #pragma unroll
    for (int d = 0; d < 4; ++d) {
        int tp = t - 3 + d;
        bool ok = tp >= 0;
        ur[d] = ok ? fr[tp] : 0.f;
        ui[d] = ok ? fim[tp] : 0.f;
    }
    float m0 = mix[(size_t)(b * 2 + 0) * NF * NT + (size_t)f * NT + t];
    float m1 = mix[(size_t)(b * 2 + 1) * NF * NT + (size_t)f * NT + t];

    float sv[4];
    #pragma unroll
    for (int i = 0; i < 4; ++i) sv[i] = 1.f / (1.f + expf(-vvec[i]));

    const float* w0p = Wt + ((size_t)(b * 2 + 0) * NT + t) * 16;
    const float* w1p = Wt + ((size_t)(b * 2 + 1) * NT + t) * 16;

    float g0[4], g1[4];
    #pragma unroll
    for (int j = 0; j < 4; ++j) { g0[j] = 0.f; g1[j] = 0.f; }
    #pragma unroll
    for (int i = 0; i < 4; ++i) {
        float a0 = ur[i] * sv[i];
        float a1 = -ui[i] * sv[i];
        #pragma unroll
        for (int j = 0; j < 4; ++j) {
            g0[j] = fmaf(a0, w0p[i * 4 + j], g0[j]);
            g1[j] = fmaf(a1, w1p[i * 4 + j], g1[j]);
        }
    }

    float Ar[16], Ai[16], br[4], bi[4], wr[4], wi[4];
    #pragma unroll
    for (int j = 0; j < 4; ++j) {
        #pragma unroll
        for (int m = 0; m < 4; ++m) {
            float e = (j == m) ? (1.0f + 1e-8f) : 1e-8f;
            Ar[j * 4 + m] = fmaf(ur[m], g0[j], e);
            Ai[j * 4 + m] = fmaf(-ui[m], g1[j], e);
        }
        br[j] = m0 * g0[j];
        bi[j] = m1 * g1[j];
    }

    csolve4(Ar, Ai, br, bi, wr, wi);

    float resr = 0.f, resi = 0.f;
    #pragma unroll
    for (int d = 0; d < 4; ++d) {
        resr += ur[d] * wr[d] - ui[d] * wi[d];
        resi += ur[d] * wi[d] + ui[d] * wr[d];
    }
    out[(size_t)(b * 2 + 0) * NF * NT + (size_t)f * NT + t] = resr;
    out[(size_t)(b * 2 + 1) * NF * NT + (size_t)f * NT + t] = resi;
}

// ---------------------------------------------------------------------------
extern "C" void kernel_launch(void* const* d_in, const int* in_sizes, int n_in,
                              void* d_out, int out_size, void* d_ws, size_t ws_size,
                              hipStream_t stream) {
    const float* far  = (const float*)d_in[0];
    const float* mix  = (const float*)d_in[1];
    const float* kcw  = (const float*)d_in[2];
    const float* kcb  = (const float*)d_in[3];
    const float* qlw  = (const float*)d_in[4];
    const float* qlb  = (const float*)d_in[5];
    const float* qng  = (const float*)d_in[6];
    const float* qnb  = (const float*)d_in[7];
    const float* klw  = (const float*)d_in[8];
    const float* klb  = (const float*)d_in[9];
    const float* kng  = (const float*)d_in[10];
    const float* knb  = (const float*)d_in[11];
    const float* qvec = (const float*)d_in[12];
    const float* kvec = (const float*)d_in[13];
    const float* vvec = (const float*)d_in[14];

    float* P  = (float*)d_ws;                       // 16*160*1000
    float* Qn = P + (size_t)NBC * NF * NT;          // 16*1003*160
    float* W  = Qn + (size_t)NBC * NTQ * NF;        // 16*1000*16
    float* out = (float*)d_out;

    k1_qproj<<<dim3(NBC, 16), 512, 0, stream>>>(far, qlw, P);
    k2_ln<<<dim3(NBC, 4), 256, 0, stream>>>(P, qlb, qng, qnb, qvec, Qn);
    k3_attn<<<dim3((NBC * NT) / 4), 256, 0, stream>>>(mix, Qn, kcw, kcb, klw, klb,
                                                      kng, knb, kvec, W);
    k4_final<<<dim3(4, NF, 8), 256, 0, stream>>>(far, mix, W, vvec, out);
}

// Round 2
// 115.656 us; speedup vs baseline: 1.5972x; 1.5972x over previous
//
#include <hip/hip_runtime.h>
#include <math.h>

#define NBC   16          // b*2
#define NF    160
#define NT    1000
#define NTQ   1003        // t rows incl. 3 pad rows at front

// ---------------------------------------------------------------------------
// k1: fused  P = ql_w @ (sgn*far)  ->  LayerNorm -> *sigmoid(q_vec)
//     writes Qn[bc][tt][f], tt = t+3 (rows 0..2 = padded LN(ql_b) rows)
// block: 512 thr = 8 waves (each wave one 20-row fo group) x 64 t
// ---------------------------------------------------------------------------
__global__ __launch_bounds__(512) void k1_qproj_ln(const float* __restrict__ far,
                                                   const float* __restrict__ qlw,
                                                   const float* __restrict__ qlb,
                                                   const float* __restrict__ qng,
                                                   const float* __restrict__ qnb,
                                                   const float* __restrict__ qvec,
                                                   float* __restrict__ Qn) {
    __shared__ float Xs[NF * 65];     // padded stride 65 -> conflict-free both axes
    __shared__ float red_s[8 * 64];
    __shared__ float red_q[8 * 64];

    const int bc = blockIdx.x;      // 0..15
    const int t0 = blockIdx.y * 64; // 0..960
    const int tid = threadIdx.x;
    const float sgn = (bc & 1) ? -1.f : 1.f;
    const float* Xb = far + (size_t)bc * NF * NT;

    // stage X tile (160 f x 64 t), sign applied
    #pragma unroll
    for (int i = 0; i < 20; ++i) {
        int o = tid + i * 512;
        int fi = o >> 6, tl0 = o & 63;
        int t = t0 + tl0;
        float v = (t < NT) ? Xb[fi * NT + t] : 0.f;
        Xs[fi * 65 + tl0] = v * sgn;
    }
    __syncthreads();

    const int g = __builtin_amdgcn_readfirstlane(tid >> 6); // wave id 0..7
    const int tl = tid & 63;
    const int fo0 = g * 20;

    float acc[20];
    #pragma unroll
    for (int u = 0; u < 20; ++u) acc[u] = 0.f;

    #pragma unroll 4
    for (int fi = 0; fi < NF; ++fi) {
        float x = Xs[fi * 65 + tl];
        #pragma unroll
        for (int u = 0; u < 20; ++u)
            acc[u] = fmaf(qlw[(fo0 + u) * NF + fi], x, acc[u]);
    }

    // per-wave LN partials from registers (v = acc + ql_b)
    float ps = 0.f, pq = 0.f;
    #pragma unroll
    for (int u = 0; u < 20; ++u) {
        float vu = acc[u] + qlb[fo0 + u];
        acc[u] = vu;
        ps += vu;
        pq = fmaf(vu, vu, pq);
    }
    red_s[g * 64 + tl] = ps;
    red_q[g * 64 + tl] = pq;
    __syncthreads();   // also guarantees all waves finished reading Xs

    float s = 0.f, q = 0.f;
    #pragma unroll
    for (int gg = 0; gg < 8; ++gg) {
        s += red_s[gg * 64 + tl];
        q += red_q[gg * 64 + tl];
    }
    float mean = s * (1.f / NF);
    float var  = q * (1.f / NF) - mean * mean;
    float inv  = 1.f / sqrtf(var + 1e-5f);

    // normalize in registers, park transposed tile in Xs
    #pragma unroll
    for (int u = 0; u < 20; ++u) {
        int fo = fo0 + u;
        float sq = 1.f / (1.f + expf(-qvec[fo]));
        Xs[fo * 65 + tl] = ((acc[u] - mean) * inv * qng[fo] + qnb[fo]) * sq;
    }
    __syncthreads();

    // coalesced write-out: Qn[bc][t+3][f], runs of 160 floats
    #pragma unroll
    for (int i = 0; i < 20; ++i) {
        int o = tid + i * 512;          // 0..10239
        int ttl = o / 160;              // 0..63
        int f = o - ttl * 160;
        int t = t0 + ttl;
        if (t < NT)
            Qn[((size_t)bc * NTQ + t + 3) * NF + f] = Xs[f * 65 + ttl];
    }

    // padded rows tt = 0..2  (input row = zeros -> LN(ql_b))
    if (t0 == 0 && tid < 3 * NF) {
        int ttp = tid / 160;
        int f = tid - ttp * 160;
        float s2 = 0.f, q2 = 0.f;
        for (int j = 0; j < NF; ++j) {
            float vj = qlb[j];
            s2 += vj;
            q2 = fmaf(vj, vj, q2);
        }
        float mn = s2 * (1.f / NF);
        float vr = q2 * (1.f / NF) - mn * mn;
        float iv = 1.f / sqrtf(vr + 1e-5f);
        float sq = 1.f / (1.f + expf(-qvec[f]));
        Qn[((size_t)bc * NTQ + ttp) * NF + f] = ((qlb[f] - mn) * iv * qng[f] + qnb[f]) * sq;
    }
}

// ---------------------------------------------------------------------------
// k3: per (b,c,t): key pipeline over f, scores (4x4), softmax -> W[site][16]
// one wave per site; lanes split the 160 f values.
// ---------------------------------------------------------------------------
__global__ __launch_bounds__(256) void k3_attn(const float* __restrict__ mix,
                                               const float* __restrict__ Qn,
                                               const float* __restrict__ kcw,
                                               const float* __restrict__ kcb,
                                               const float* __restrict__ klw,
                                               const float* __restrict__ klb,
                                               const float* __restrict__ kng,
                                               const float* __restrict__ knb,
                                               const float* __restrict__ kvec,
                                               float* __restrict__ W) {
    const int wv = __builtin_amdgcn_readfirstlane((int)threadIdx.x >> 6);
    const int lane = threadIdx.x & 63;
    const int site = blockIdx.x * 4 + wv;   // bc*1000 + t
    if (site >= NBC * NT) return;
    const int bc = site / NT;
    const int t = site - bc * NT;
    const int b = bc >> 1, c = bc & 1;

    float kw0[4], kw1[4], kb[4], klwm[16], klbv[4], kngv[4], knbv[4], sigk[4];
    #pragma unroll
    for (int j = 0; j < 4; ++j) {
        kw0[j] = kcw[(4 * c + j) * 2 + 0];
        kw1[j] = kcw[(4 * c + j) * 2 + 1];
        kb[j]  = kcb[4 * c + j];
        klbv[j] = klb[j];
        kngv[j] = kng[j];
        knbv[j] = knb[j];
        sigk[j] = 0.5f / (1.f + expf(-kvec[j]));   // sigmoid(k_vec)/sqrt(k)
    }
    #pragma unroll
    for (int x = 0; x < 16; ++x) klwm[x] = klw[x];

    float s[16];
    #pragma unroll
    for (int x = 0; x < 16; ++x) s[x] = 0.f;

    const float* mixb = mix + (size_t)(b * 2) * NF * NT;
    const float* Qb = Qn + (size_t)bc * NTQ * NF;

    #pragma unroll
    for (int rep = 0; rep < 3; ++rep) {
        int f = lane + rep * 64;
        if (f < NF) {
            float m0 = mixb[f * NT + t];
            float m1 = mixb[NF * NT + f * NT + t];
            float kraw[4], klin[4];
            #pragma unroll
            for (int j = 0; j < 4; ++j)
                kraw[j] = fmaf(kw0[j], m0, fmaf(kw1[j], m1, kb[j]));
            #pragma unroll
            for (int jo = 0; jo < 4; ++jo) {
                float a = klbv[jo];
                #pragma unroll
                for (int ji = 0; ji < 4; ++ji) a = fmaf(klwm[jo * 4 + ji], kraw[ji], a);
                klin[jo] = a;
            }
            float mn = 0.25f * (klin[0] + klin[1] + klin[2] + klin[3]);
            float d0 = klin[0] - mn, d1 = klin[1] - mn, d2 = klin[2] - mn, d3 = klin[3] - mn;
            float var = 0.25f * (d0 * d0 + d1 * d1 + d2 * d2 + d3 * d3);
            float inv = 1.f / sqrtf(var + 1e-5f);
            float kn[4];
            kn[0] = (d0 * inv * kngv[0] + knbv[0]) * sigk[0];
            kn[1] = (d1 * inv * kngv[1] + knbv[1]) * sigk[1];
            kn[2] = (d2 * inv * kngv[2] + knbv[2]) * sigk[2];
            kn[3] = (d3 * inv * kngv[3] + knbv[3]) * sigk[3];

            float q0 = Qb[(t + 0) * NF + f];
            float q1 = Qb[(t + 1) * NF + f];
            float q2 = Qb[(t + 2) * NF + f];
            float q3 = Qb[(t + 3) * NF + f];
            #pragma unroll
            for (int j = 0; j < 4; ++j) {
                s[0 * 4 + j] = fmaf(q0, kn[j], s[0 * 4 + j]);
                s[1 * 4 + j] = fmaf(q1, kn[j], s[1 * 4 + j]);
                s[2 * 4 + j] = fmaf(q2, kn[j], s[2 * 4 + j]);
                s[3 * 4 + j] = fmaf(q3, kn[j], s[3 * 4 + j]);
            }
        }
    }

    #pragma unroll
    for (int off = 1; off < 64; off <<= 1) {
        #pragma unroll
        for (int x = 0; x < 16; ++x) s[x] += __shfl_xor(s[x], off, 64);
    }

    float wv16[16];
    #pragma unroll
    for (int i = 0; i < 4; ++i) {
        float a = s[i * 4 + 0], b2 = s[i * 4 + 1], c2 = s[i * 4 + 2], d2 = s[i * 4 + 3];
        float mx = fmaxf(fmaxf(a, b2), fmaxf(c2, d2));
        float e0 = expf(a - mx), e1 = expf(b2 - mx), e2 = expf(c2 - mx), e3 = expf(d2 - mx);
        float inv = 1.f / (e0 + e1 + e2 + e3);
        wv16[i * 4 + 0] = e0 * inv;
        wv16[i * 4 + 1] = e1 * inv;
        wv16[i * 4 + 2] = e2 * inv;
        wv16[i * 4 + 3] = e3 * inv;
    }
    if (lane < 16) {
        float v = 0.f;
        #pragma unroll
        for (int x = 0; x < 16; ++x) v = (lane == x) ? wv16[x] : v;
        W[(size_t)site * 16 + lane] = v;
    }
}

// ---------------------------------------------------------------------------
// complex 4x4 solve, partial pivoting (cabs1), fully unrolled
// ---------------------------------------------------------------------------
__device__ __forceinline__ void csolve4(float Ar[16], float Ai[16],
                                        float br[4], float bi[4],
                                        float wr[4], float wi[4]) {
    #pragma unroll
    for (int col = 0; col < 4; ++col) {
        #pragma unroll
        for (int r = col + 1; r < 4; ++r) {
            float cp = fabsf(Ar[col * 4 + col]) + fabsf(Ai[col * 4 + col]);
            float cr = fabsf(Ar[r * 4 + col]) + fabsf(Ai[r * 4 + col]);
            bool sw = cr > cp;
            #pragma unroll
            for (int m = col; m < 4; ++m) {
                float a0 = Ar[col * 4 + m], a1 = Ar[r * 4 + m];
                Ar[col * 4 + m] = sw ? a1 : a0;
                Ar[r * 4 + m]   = sw ? a0 : a1;
                float c0 = Ai[col * 4 + m], c1 = Ai[r * 4 + m];
                Ai[col * 4 + m] = sw ? c1 : c0;
                Ai[r * 4 + m]   = sw ? c0 : c1;
            }
            float b0 = br[col], b1 = br[r];
            br[col] = sw ? b1 : b0; br[r] = sw ? b0 : b1;
            float d0 = bi[col], d1 = bi[r];
            bi[col] = sw ? d1 : d0; bi[r] = sw ? d0 : d1;
        }
        float pr = Ar[col * 4 + col], pi = Ai[col * 4 + col];
        float den = 1.f / (pr * pr + pi * pi);
        #pragma unroll
        for (int r = col + 1; r < 4; ++r) {
            float nr = Ar[r * 4 + col], ni = Ai[r * 4 + col];
            float fr = (nr * pr + ni * pi) * den;
            float fi = (ni * pr - nr * pi) * den;
            #pragma unroll
            for (int m = col + 1; m < 4; ++m) {
                float tr = Ar[col * 4 + m], ti = Ai[col * 4 + m];
                Ar[r * 4 + m] -= fr * tr - fi * ti;
                Ai[r * 4 + m] -= fr * ti + fi * tr;
            }
            float tr = br[col], ti = bi[col];
            br[r] -= fr * tr - fi * ti;
            bi[r] -= fr * ti + fi * tr;
        }
    }
    #pragma unroll
    for (int col = 3; col >= 0; --col) {
        float sr = br[col], si = bi[col];
        #pragma unroll
        for (int m = col + 1; m < 4; ++m) {
            float tr = Ar[col * 4 + m], ti = Ai[col * 4 + m];
            sr -= tr * wr[m] - ti * wi[m];
            si -= tr * wi[m] + ti * wr[m];
        }
        float pr = Ar[col * 4 + col], pi = Ai[col * 4 + col];
        float den = 1.f / (pr * pr + pi * pi);
        wr[col] = (sr * pr + si * pi) * den;
        wi[col] = (si * pr - sr * pi) * den;
    }
}

// ---------------------------------------------------------------------------
// k4: per (b,f,t): build rank-1 value/out, assemble A,rhs, solve, Wiener sum
// ---------------------------------------------------------------------------
__global__ __launch_bounds__(256) void k4_final(const float* __restrict__ far,
                                                const float* __restrict__ mix,
                                                const float* __restrict__ Wt,
                                                const float* __restrict__ vvec,
                                                float* __restrict__ out) {
    const int t = blockIdx.x * 256 + threadIdx.x;
    const int f = blockIdx.y;
    const int b = blockIdx.z;
    if (t >= NT) return;

    const float* fr  = far + (size_t)(b * 2 + 0) * NF * NT + (size_t)f * NT;
    const float* fim = far + (size_t)(b * 2 + 1) * NF * NT + (size_t)f * NT;
    float ur[4], ui[4];
    #pragma unroll
    for (int d = 0; d < 4; ++d) {
        int tp = t - 3 + d;
        bool ok = tp >= 0;
        ur[d] = ok ? fr[tp] : 0.f;
        ui[d] = ok ? fim[tp] : 0.f;
    }
    float m0 = mix[(size_t)(b * 2 + 0) * NF * NT + (size_t)f * NT + t];
    float m1 = mix[(size_t)(b * 2 + 1) * NF * NT + (size_t)f * NT + t];

    float sv[4];
    #pragma unroll
    for (int i = 0; i < 4; ++i) sv[i] = 1.f / (1.f + expf(-vvec[i]));

    const float* w0p = Wt + ((size_t)(b * 2 + 0) * NT + t) * 16;
    const float* w1p = Wt + ((size_t)(b * 2 + 1) * NT + t) * 16;

    float g0[4], g1[4];
    #pragma unroll
    for (int j = 0; j < 4; ++j) { g0[j] = 0.f; g1[j] = 0.f; }
    #pragma unroll
    for (int i = 0; i < 4; ++i) {
        float a0 = ur[i] * sv[i];
        float a1 = -ui[i] * sv[i];
        #pragma unroll
        for (int j = 0; j < 4; ++j) {
            g0[j] = fmaf(a0, w0p[i * 4 + j], g0[j]);
            g1[j] = fmaf(a1, w1p[i * 4 + j], g1[j]);
        }
    }

    float Ar[16], Ai[16], br[4], bi[4], wr[4], wi[4];
    #pragma unroll
    for (int j = 0; j < 4; ++j) {
        #pragma unroll
        for (int m = 0; m < 4; ++m) {
            float e = (j == m) ? (1.0f + 1e-8f) : 1e-8f;
            Ar[j * 4 + m] = fmaf(ur[m], g0[j], e);
            Ai[j * 4 + m] = fmaf(-ui[m], g1[j], e);
        }
        br[j] = m0 * g0[j];
        bi[j] = m1 * g1[j];
    }

    csolve4(Ar, Ai, br, bi, wr, wi);

    float resr = 0.f, resi = 0.f;
    #pragma unroll
    for (int d = 0; d < 4; ++d) {
        resr += ur[d] * wr[d] - ui[d] * wi[d];
        resi += ur[d] * wi[d] + ui[d] * wr[d];
    }
    out[(size_t)(b * 2 + 0) * NF * NT + (size_t)f * NT + t] = resr;
    out[(size_t)(b * 2 + 1) * NF * NT + (size_t)f * NT + t] = resi;
}

// ---------------------------------------------------------------------------
extern "C" void kernel_launch(void* const* d_in, const int* in_sizes, int n_in,
                              void* d_out, int out_size, void* d_ws, size_t ws_size,
                              hipStream_t stream) {
    const float* far  = (const float*)d_in[0];
    const float* mix  = (const float*)d_in[1];
    const float* kcw  = (const float*)d_in[2];
    const float* kcb  = (const float*)d_in[3];
    const float* qlw  = (const float*)d_in[4];
    const float* qlb  = (const float*)d_in[5];
    const float* qng  = (const float*)d_in[6];
    const float* qnb  = (const float*)d_in[7];
    const float* klw  = (const float*)d_in[8];
    const float* klb  = (const float*)d_in[9];
    const float* kng  = (const float*)d_in[10];
    const float* knb  = (const float*)d_in[11];
    const float* qvec = (const float*)d_in[12];
    const float* kvec = (const float*)d_in[13];
    const float* vvec = (const float*)d_in[14];

    float* Qn = (float*)d_ws;                       // 16*1003*160
    float* W  = Qn + (size_t)NBC * NTQ * NF;        // 16*1000*16
    float* out = (float*)d_out;

    k1_qproj_ln<<<dim3(NBC, 16), 512, 0, stream>>>(far, qlw, qlb, qng, qnb, qvec, Qn);
    k3_attn<<<dim3((NBC * NT) / 4), 256, 0, stream>>>(mix, Qn, kcw, kcb, klw, klb,
                                                      kng, knb, kvec, W);
    k4_final<<<dim3(4, NF, 8), 256, 0, stream>>>(far, mix, W, vvec, out);
}

// Round 3
// 86.493 us; speedup vs baseline: 2.1357x; 1.3372x over previous
//
#include <hip/hip_runtime.h>
#include <math.h>

#define NBC   16          // b*2
#define NF    160
#define NT    1000
#define NTQ   1003        // t rows incl. 3 pad rows at front
#define WSTR  164         // Wt row stride (floats): 164*4=656B = 16B*41 -> b128-aligned rows

// ---------------------------------------------------------------------------
// k1: fused  P = ql_w @ (sgn*far)  ->  LayerNorm -> *sigmoid(q_vec)
//     writes Qn[bc][tt][f], tt = t+3 (rows 0..2 = padded LN(ql_b) rows)
// block: 512 thr = 8 waves (each wave one 20-row fo group) x 64 t
// ql_w staged TRANSPOSED in LDS -> per-fi weights are 5 broadcast b128 reads
// (kills the scalar-cache thrash that made v1 latency-bound at 12% VALUBusy)
// ---------------------------------------------------------------------------
__global__ __launch_bounds__(512) void k1_qproj_ln(const float* __restrict__ far,
                                                   const float* __restrict__ qlw,
                                                   const float* __restrict__ qlb,
                                                   const float* __restrict__ qng,
                                                   const float* __restrict__ qnb,
                                                   const float* __restrict__ qvec,
                                                   float* __restrict__ Qn) {
    __shared__ float Ws[NF * WSTR];   // Wt[fi][fo]
    __shared__ float Xs[NF * 65];     // X[fi][tl], padded stride 65
    __shared__ float red_s[8 * 64];
    __shared__ float red_q[8 * 64];

    const int bc = blockIdx.x;      // 0..15
    const int t0 = blockIdx.y * 64; // 0..960
    const int tid = threadIdx.x;
    const float sgn = (bc & 1) ? -1.f : 1.f;
    const float* Xb = far + (size_t)bc * NF * NT;

    // stage Wt[fi][fo] = qlw[fo][fi]  (coalesced global reads, 50/thread)
    #pragma unroll
    for (int i = 0; i < 50; ++i) {
        int o = tid + i * 512;          // 0..25599
        int fo = o / 160;
        int fi = o - fo * 160;
        Ws[fi * WSTR + fo] = qlw[o];
    }

    // stage X tile (160 f x 64 t), sign applied
    #pragma unroll
    for (int i = 0; i < 20; ++i) {
        int o = tid + i * 512;
        int fi = o >> 6, tl0 = o & 63;
        int t = t0 + tl0;
        float v = (t < NT) ? Xb[fi * NT + t] : 0.f;
        Xs[fi * 65 + tl0] = v * sgn;
    }
    __syncthreads();

    const int g = __builtin_amdgcn_readfirstlane(tid >> 6); // wave id 0..7
    const int tl = tid & 63;
    const int fo0 = g * 20;

    float acc[20];
    #pragma unroll
    for (int u = 0; u < 20; ++u) acc[u] = 0.f;

    #pragma unroll 4
    for (int fi = 0; fi < NF; ++fi) {
        float x = Xs[fi * 65 + tl];
        const float* wrow = &Ws[fi * WSTR + fo0];
        float4 w0 = *(const float4*)(wrow + 0);
        float4 w1 = *(const float4*)(wrow + 4);
        float4 w2 = *(const float4*)(wrow + 8);
        float4 w3 = *(const float4*)(wrow + 12);
        float4 w4 = *(const float4*)(wrow + 16);
        acc[0]  = fmaf(w0.x, x, acc[0]);
        acc[1]  = fmaf(w0.y, x, acc[1]);
        acc[2]  = fmaf(w0.z, x, acc[2]);
        acc[3]  = fmaf(w0.w, x, acc[3]);
        acc[4]  = fmaf(w1.x, x, acc[4]);
        acc[5]  = fmaf(w1.y, x, acc[5]);
        acc[6]  = fmaf(w1.z, x, acc[6]);
        acc[7]  = fmaf(w1.w, x, acc[7]);
        acc[8]  = fmaf(w2.x, x, acc[8]);
        acc[9]  = fmaf(w2.y, x, acc[9]);
        acc[10] = fmaf(w2.z, x, acc[10]);
        acc[11] = fmaf(w2.w, x, acc[11]);
        acc[12] = fmaf(w3.x, x, acc[12]);
        acc[13] = fmaf(w3.y, x, acc[13]);
        acc[14] = fmaf(w3.z, x, acc[14]);
        acc[15] = fmaf(w3.w, x, acc[15]);
        acc[16] = fmaf(w4.x, x, acc[16]);
        acc[17] = fmaf(w4.y, x, acc[17]);
        acc[18] = fmaf(w4.z, x, acc[18]);
        acc[19] = fmaf(w4.w, x, acc[19]);
    }

    // per-wave LN partials from registers (v = acc + ql_b)
    float ps = 0.f, pq = 0.f;
    #pragma unroll
    for (int u = 0; u < 20; ++u) {
        float vu = acc[u] + qlb[fo0 + u];
        acc[u] = vu;
        ps += vu;
        pq = fmaf(vu, vu, pq);
    }
    red_s[g * 64 + tl] = ps;
    red_q[g * 64 + tl] = pq;
    __syncthreads();   // also guarantees all waves finished reading Xs

    float s = 0.f, q = 0.f;
    #pragma unroll
    for (int gg = 0; gg < 8; ++gg) {
        s += red_s[gg * 64 + tl];
        q += red_q[gg * 64 + tl];
    }
    float mean = s * (1.f / NF);
    float var  = q * (1.f / NF) - mean * mean;
    float inv  = 1.f / sqrtf(var + 1e-5f);

    // normalize in registers, park transposed tile in Xs
    #pragma unroll
    for (int u = 0; u < 20; ++u) {
        int fo = fo0 + u;
        float sq = 1.f / (1.f + expf(-qvec[fo]));
        Xs[fo * 65 + tl] = ((acc[u] - mean) * inv * qng[fo] + qnb[fo]) * sq;
    }
    __syncthreads();

    // coalesced write-out: Qn[bc][t+3][f], runs of 160 floats
    #pragma unroll
    for (int i = 0; i < 20; ++i) {
        int o = tid + i * 512;          // 0..10239
        int ttl = o / 160;              // 0..63
        int f = o - ttl * 160;
        int t = t0 + ttl;
        if (t < NT)
            Qn[((size_t)bc * NTQ + t + 3) * NF + f] = Xs[f * 65 + ttl];
    }

    // padded rows tt = 0..2  (input row = zeros -> LN(ql_b))
    if (t0 == 0 && tid < 3 * NF) {
        int ttp = tid / 160;
        int f = tid - ttp * 160;
        float s2 = 0.f, q2 = 0.f;
        for (int j = 0; j < NF; ++j) {
            float vj = qlb[j];
            s2 += vj;
            q2 = fmaf(vj, vj, q2);
        }
        float mn = s2 * (1.f / NF);
        float vr = q2 * (1.f / NF) - mn * mn;
        float iv = 1.f / sqrtf(vr + 1e-5f);
        float sq = 1.f / (1.f + expf(-qvec[f]));
        Qn[((size_t)bc * NTQ + ttp) * NF + f] = ((qlb[f] - mn) * iv * qng[f] + qnb[f]) * sq;
    }
}

// ---------------------------------------------------------------------------
// k3: per (b,c,t): key pipeline over f, scores (4x4), softmax -> W[site][16]
// one wave per site; lanes split the 160 f values.
// ---------------------------------------------------------------------------
__global__ __launch_bounds__(256) void k3_attn(const float* __restrict__ mix,
                                               const float* __restrict__ Qn,
                                               const float* __restrict__ kcw,
                                               const float* __restrict__ kcb,
                                               const float* __restrict__ klw,
                                               const float* __restrict__ klb,
                                               const float* __restrict__ kng,
                                               const float* __restrict__ knb,
                                               const float* __restrict__ kvec,
                                               float* __restrict__ W) {
    const int wv = __builtin_amdgcn_readfirstlane((int)threadIdx.x >> 6);
    const int lane = threadIdx.x & 63;
    const int site = blockIdx.x * 4 + wv;   // bc*1000 + t
    if (site >= NBC * NT) return;
    const int bc = site / NT;
    const int t = site - bc * NT;
    const int b = bc >> 1, c = bc & 1;

    float kw0[4], kw1[4], kb[4], klwm[16], klbv[4], kngv[4], knbv[4], sigk[4];
    #pragma unroll
    for (int j = 0; j < 4; ++j) {
        kw0[j] = kcw[(4 * c + j) * 2 + 0];
        kw1[j] = kcw[(4 * c + j) * 2 + 1];
        kb[j]  = kcb[4 * c + j];
        klbv[j] = klb[j];
        kngv[j] = kng[j];
        knbv[j] = knb[j];
        sigk[j] = 0.5f / (1.f + expf(-kvec[j]));   // sigmoid(k_vec)/sqrt(k)
    }
    #pragma unroll
    for (int x = 0; x < 16; ++x) klwm[x] = klw[x];

    float s[16];
    #pragma unroll
    for (int x = 0; x < 16; ++x) s[x] = 0.f;

    const float* mixb = mix + (size_t)(b * 2) * NF * NT;
    const float* Qb = Qn + (size_t)bc * NTQ * NF;

    #pragma unroll
    for (int rep = 0; rep < 3; ++rep) {
        int f = lane + rep * 64;
        if (f < NF) {
            float m0 = mixb[f * NT + t];
            float m1 = mixb[NF * NT + f * NT + t];
            float kraw[4], klin[4];
            #pragma unroll
            for (int j = 0; j < 4; ++j)
                kraw[j] = fmaf(kw0[j], m0, fmaf(kw1[j], m1, kb[j]));
            #pragma unroll
            for (int jo = 0; jo < 4; ++jo) {
                float a = klbv[jo];
                #pragma unroll
                for (int ji = 0; ji < 4; ++ji) a = fmaf(klwm[jo * 4 + ji], kraw[ji], a);
                klin[jo] = a;
            }
            float mn = 0.25f * (klin[0] + klin[1] + klin[2] + klin[3]);
            float d0 = klin[0] - mn, d1 = klin[1] - mn, d2 = klin[2] - mn, d3 = klin[3] - mn;
            float var = 0.25f * (d0 * d0 + d1 * d1 + d2 * d2 + d3 * d3);
            float inv = 1.f / sqrtf(var + 1e-5f);
            float kn[4];
            kn[0] = (d0 * inv * kngv[0] + knbv[0]) * sigk[0];
            kn[1] = (d1 * inv * kngv[1] + knbv[1]) * sigk[1];
            kn[2] = (d2 * inv * kngv[2] + knbv[2]) * sigk[2];
            kn[3] = (d3 * inv * kngv[3] + knbv[3]) * sigk[3];

            float q0 = Qb[(t + 0) * NF + f];
            float q1 = Qb[(t + 1) * NF + f];
            float q2 = Qb[(t + 2) * NF + f];
            float q3 = Qb[(t + 3) * NF + f];
            #pragma unroll
            for (int j = 0; j < 4; ++j) {
                s[0 * 4 + j] = fmaf(q0, kn[j], s[0 * 4 + j]);
                s[1 * 4 + j] = fmaf(q1, kn[j], s[1 * 4 + j]);
                s[2 * 4 + j] = fmaf(q2, kn[j], s[2 * 4 + j]);
                s[3 * 4 + j] = fmaf(q3, kn[j], s[3 * 4 + j]);
            }
        }
    }

    #pragma unroll
    for (int off = 1; off < 64; off <<= 1) {
        #pragma unroll
        for (int x = 0; x < 16; ++x) s[x] += __shfl_xor(s[x], off, 64);
    }

    float wv16[16];
    #pragma unroll
    for (int i = 0; i < 4; ++i) {
        float a = s[i * 4 + 0], b2 = s[i * 4 + 1], c2 = s[i * 4 + 2], d2 = s[i * 4 + 3];
        float mx = fmaxf(fmaxf(a, b2), fmaxf(c2, d2));
        float e0 = expf(a - mx), e1 = expf(b2 - mx), e2 = expf(c2 - mx), e3 = expf(d2 - mx);
        float inv = 1.f / (e0 + e1 + e2 + e3);
        wv16[i * 4 + 0] = e0 * inv;
        wv16[i * 4 + 1] = e1 * inv;
        wv16[i * 4 + 2] = e2 * inv;
        wv16[i * 4 + 3] = e3 * inv;
    }
    if (lane < 16) {
        float v = 0.f;
        #pragma unroll
        for (int x = 0; x < 16; ++x) v = (lane == x) ? wv16[x] : v;
        W[(size_t)site * 16 + lane] = v;
    }
}

// ---------------------------------------------------------------------------
// complex 4x4 solve, partial pivoting (cabs1), fully unrolled
// ---------------------------------------------------------------------------
__device__ __forceinline__ void csolve4(float Ar[16], float Ai[16],
                                        float br[4], float bi[4],
                                        float wr[4], float wi[4]) {
    #pragma unroll
    for (int col = 0; col < 4; ++col) {
        #pragma unroll
        for (int r = col + 1; r < 4; ++r) {
            float cp = fabsf(Ar[col * 4 + col]) + fabsf(Ai[col * 4 + col]);
            float cr = fabsf(Ar[r * 4 + col]) + fabsf(Ai[r * 4 + col]);
            bool sw = cr > cp;
            #pragma unroll
            for (int m = col; m < 4; ++m) {
                float a0 = Ar[col * 4 + m], a1 = Ar[r * 4 + m];
                Ar[col * 4 + m] = sw ? a1 : a0;
                Ar[r * 4 + m]   = sw ? a0 : a1;
                float c0 = Ai[col * 4 + m], c1 = Ai[r * 4 + m];
                Ai[col * 4 + m] = sw ? c1 : c0;
                Ai[r * 4 + m]   = sw ? c0 : c1;
            }
            float b0 = br[col], b1 = br[r];
            br[col] = sw ? b1 : b0; br[r] = sw ? b0 : b1;
            float d0 = bi[col], d1 = bi[r];
            bi[col] = sw ? d1 : d0; bi[r] = sw ? d0 : d1;
        }
        float pr = Ar[col * 4 + col], pi = Ai[col * 4 + col];
        float den = 1.f / (pr * pr + pi * pi);
        #pragma unroll
        for (int r = col + 1; r < 4; ++r) {
            float nr = Ar[r * 4 + col], ni = Ai[r * 4 + col];
            float fr = (nr * pr + ni * pi) * den;
            float fi = (ni * pr - nr * pi) * den;
            #pragma unroll
            for (int m = col + 1; m < 4; ++m) {
                float tr = Ar[col * 4 + m], ti = Ai[col * 4 + m];
                Ar[r * 4 + m] -= fr * tr - fi * ti;
                Ai[r * 4 + m] -= fr * ti + fi * tr;
            }
            float tr = br[col], ti = bi[col];
            br[r] -= fr * tr - fi * ti;
            bi[r] -= fr * ti + fi * tr;
        }
    }
    #pragma unroll
    for (int col = 3; col >= 0; --col) {
        float sr = br[col], si = bi[col];
        #pragma unroll
        for (int m = col + 1; m < 4; ++m) {
            float tr = Ar[col * 4 + m], ti = Ai[col * 4 + m];
            sr -= tr * wr[m] - ti * wi[m];
            si -= tr * wi[m] + ti * wr[m];
        }
        float pr = Ar[col * 4 + col], pi = Ai[col * 4 + col];
        float den = 1.f / (pr * pr + pi * pi);
        wr[col] = (sr * pr + si * pi) * den;
        wi[col] = (si * pr - sr * pi) * den;
    }
}

// ---------------------------------------------------------------------------
// k4: per (b,f,t): build rank-1 value/out, assemble A,rhs, solve, Wiener sum
// ---------------------------------------------------------------------------
__global__ __launch_bounds__(256) void k4_final(const float* __restrict__ far,
                                                const float* __restrict__ mix,
                                                const float* __restrict__ Wt,
                                                const float* __restrict__ vvec,
                                                float* __restrict__ out) {
    const int t = blockIdx.x * 256 + threadIdx.x;
    const int f = blockIdx.y;
    const int b = blockIdx.z;
    if (t >= NT) return;

    const float* fr  = far + (size_t)(b * 2 + 0) * NF * NT + (size_t)f * NT;
    const float* fim = far + (size_t)(b * 2 + 1) * NF * NT + (size_t)f * NT;
    float ur[4], ui[4];
    #pragma unroll
    for (int d = 0; d < 4; ++d) {
        int tp = t - 3 + d;
        bool ok = tp >= 0;
        ur[d] = ok ? fr[tp] : 0.f;
        ui[d] = ok ? fim[tp] : 0.f;
    }
    float m0 = mix[(size_t)(b * 2 + 0) * NF * NT + (size_t)f * NT + t];
    float m1 = mix[(size_t)(b * 2 + 1) * NF * NT + (size_t)f * NT + t];

    float sv[4];
    #pragma unroll
    for (int i = 0; i < 4; ++i) sv[i] = 1.f / (1.f + expf(-vvec[i]));

    const float* w0p = Wt + ((size_t)(b * 2 + 0) * NT + t) * 16;
    const float* w1p = Wt + ((size_t)(b * 2 + 1) * NT + t) * 16;

    float g0[4], g1[4];
    #pragma unroll
    for (int j = 0; j < 4; ++j) { g0[j] = 0.f; g1[j] = 0.f; }
    #pragma unroll
    for (int i = 0; i < 4; ++i) {
        float a0 = ur[i] * sv[i];
        float a1 = -ui[i] * sv[i];
        #pragma unroll
        for (int j = 0; j < 4; ++j) {
            g0[j] = fmaf(a0, w0p[i * 4 + j], g0[j]);
            g1[j] = fmaf(a1, w1p[i * 4 + j], g1[j]);
        }
    }

    float Ar[16], Ai[16], br[4], bi[4], wr[4], wi[4];
    #pragma unroll
    for (int j = 0; j < 4; ++j) {
        #pragma unroll
        for (int m = 0; m < 4; ++m) {
            float e = (j == m) ? (1.0f + 1e-8f) : 1e-8f;
            Ar[j * 4 + m] = fmaf(ur[m], g0[j], e);
            Ai[j * 4 + m] = fmaf(-ui[m], g1[j], e);
        }
        br[j] = m0 * g0[j];
        bi[j] = m1 * g1[j];
    }

    csolve4(Ar, Ai, br, bi, wr, wi);

    float resr = 0.f, resi = 0.f;
    #pragma unroll
    for (int d = 0; d < 4; ++d) {
        resr += ur[d] * wr[d] - ui[d] * wi[d];
        resi += ur[d] * wi[d] + ui[d] * wr[d];
    }
    out[(size_t)(b * 2 + 0) * NF * NT + (size_t)f * NT + t] = resr;
    out[(size_t)(b * 2 + 1) * NF * NT + (size_t)f * NT + t] = resi;
}

// ---------------------------------------------------------------------------
extern "C" void kernel_launch(void* const* d_in, const int* in_sizes, int n_in,
                              void* d_out, int out_size, void* d_ws, size_t ws_size,
                              hipStream_t stream) {
    const float* far  = (const float*)d_in[0];
    const float* mix  = (const float*)d_in[1];
    const float* kcw  = (const float*)d_in[2];
    const float* kcb  = (const float*)d_in[3];
    const float* qlw  = (const float*)d_in[4];
    const float* qlb  = (const float*)d_in[5];
    const float* qng  = (const float*)d_in[6];
    const float* qnb  = (const float*)d_in[7];
    const float* klw  = (const float*)d_in[8];
    const float* klb  = (const float*)d_in[9];
    const float* kng  = (const float*)d_in[10];
    const float* knb  = (const float*)d_in[11];
    const float* qvec = (const float*)d_in[12];
    const float* kvec = (const float*)d_in[13];
    const float* vvec = (const float*)d_in[14];

    float* Qn = (float*)d_ws;                       // 16*1003*160
    float* W  = Qn + (size_t)NBC * NTQ * NF;        // 16*1000*16
    float* out = (float*)d_out;

    k1_qproj_ln<<<dim3(NBC, 16), 512, 0, stream>>>(far, qlw, qlb, qng, qnb, qvec, Qn);
    k3_attn<<<dim3((NBC * NT) / 4), 256, 0, stream>>>(mix, Qn, kcw, kcb, klw, klb,
                                                      kng, knb, kvec, W);
    k4_final<<<dim3(4, NF, 8), 256, 0, stream>>>(far, mix, W, vvec, out);
}